// Round 3
// baseline (1456.370 us; speedup 1.0000x reference)
//
#include <hip/hip_runtime.h>
#include <hip/hip_fp16.h>

// S=2048, B=32, H=1024.
// out[b][s] = softmax_s( sum_h tanh( (enc[s][b] @ We)[h] + hproj[b][h] ) * v[h] )
//
// GEMM: M = 65536 rows (K-contiguous), K = 2048, N = 1024.
// Block = 512 threads (8 waves), M-slab = 64 rows, full N per block.
// Wave w owns nt=w (128 cols): acc 4(m) x 8(n) frags (128 VGPR).
// A (enc f32): staged to LDS as f16 once per block-kt (reg load + cvt +
//   ds_write, double-buffered, one cheap barrier per kt).
// B (packed f16 We, 4 MB, L2-resident): loaded DIRECTLY into VGPR fragments
//   from global per wave per kt -- no LDS, no barrier coupling; compiler
//   pipelines the 8 dwordx4 loads against the 32 MFMAs with graduated vmcnt.

typedef _Float16 half8 __attribute__((ext_vector_type(8)));
typedef float floatx4 __attribute__((ext_vector_type(4)));
typedef float f32x4 __attribute__((ext_vector_type(4)));

constexpr int SEQ = 2048;
constexpr int BAT = 32;
constexpr int HID = 1024;
constexpr int KDIM = 2048;
constexpr int MTOT = SEQ * BAT;   // 65536
constexpr int KT = 64;            // K tiles of 32

constexpr int A_PITCH = 64 * 16 + 16; // 1040 B per fg group (pad breaks bank alias)
constexpr int A_BUF = 4 * A_PITCH;    // 4160 B per buffer

// ---------------------------------------------------------------------------
// Pack We into fp16 chunks: packB[((nt*64+kt)*512 + fg*128 + n)*8 + j]
//   = We[kt*32 + fg*8 + j][nt*128 + n]
// This is exactly the per-lane B-fragment order of mfma_f32_16x16x32_f16.
// ---------------------------------------------------------------------------
__global__ __launch_bounds__(256) void pack_b_kernel(const float* __restrict__ W,
                                                     _Float16* __restrict__ pb) {
    int t = blockIdx.x * blockDim.x + threadIdx.x;   // 0..262143
    int nt = t >> 15;
    int rem = t & 32767;
    int kt = rem >> 9;
    int c = rem & 511;
    int g = c >> 7;
    int n = c & 127;
    int h = nt * 128 + n;
    int e0 = kt * 32 + g * 8;
    const float* src = W + (size_t)(1024 + e0) * 1024 + h;
    union { _Float16 hh[8]; uint4 u; } tmp;
#pragma unroll
    for (int j = 0; j < 8; ++j) tmp.hh[j] = (_Float16)src[(size_t)j * 1024];
    *(uint4*)(pb + (size_t)t * 8) = tmp.u;
}

// ---------------------------------------------------------------------------
// hproj[b][h] = hidden[b] . W[:,h] + bias[h]. 4-way K-split, 512 blocks.
// ---------------------------------------------------------------------------
__global__ __launch_bounds__(256) void hproj_kernel(const float* __restrict__ hidden,
                                                    const float* __restrict__ W,
                                                    const float* __restrict__ bias,
                                                    float* __restrict__ hp) {
    int b = blockIdx.x;                 // 0..31
    int h0 = blockIdx.y * 64;           // 16 y-blocks
    int hl = threadIdx.x & 63;
    int ks = threadIdx.x >> 6;          // 0..3
    const float* hr = hidden + b * HID + ks * 256;
    const float* wc = W + (size_t)(ks * 256) * HID + h0 + hl;
    float acc = 0.0f;
#pragma unroll 8
    for (int e = 0; e < 256; ++e) acc += hr[e] * wc[(size_t)e * HID];
    __shared__ float red[256];
    red[threadIdx.x] = acc;
    __syncthreads();
    if (threadIdx.x < 64)
        hp[b * HID + h0 + threadIdx.x] = red[threadIdx.x] + red[64 + threadIdx.x] +
                                         red[128 + threadIdx.x] + red[192 + threadIdx.x] +
                                         bias[h0 + threadIdx.x];
}

// ---------------------------------------------------------------------------
// Main fused kernel.
// ---------------------------------------------------------------------------
__global__ __launch_bounds__(512, 2) void attn_gemm_kernel(
    const float* __restrict__ enc, const _Float16* __restrict__ pb,
    const float* __restrict__ hp, const float* __restrict__ v,
    float* __restrict__ score) {
    __shared__ char smem[2 * A_BUF];
    char* sA0 = smem;
    char* sA1 = smem + A_BUF;

    const int tid = threadIdx.x;
    const int lane = tid & 63;
    const int wv = tid >> 6;            // 0..7 == nt
    const int mt = blockIdx.x;          // 0..1023
    const size_t r0 = (size_t)mt * 64;
    const int fm = lane & 15;
    const int fg = lane >> 4;

    // A staging: thread loads one float4 of the 64x32 f32 tile per kt.
    const int arow = tid >> 3;          // 0..63
    const int ac4 = tid & 7;            // float4 col within the 32-k tile
    const f32x4* agp = (const f32x4*)(enc + (r0 + arow) * KDIM) + ac4;
    const int awoff = (ac4 >> 1) * A_PITCH + arow * 16 + (ac4 & 1) * 8;

    // B fragments: direct from packed global (L2-resident).
    // byte offset = wv*KT*8192 + kt*8192 + fg*2048 + j*256 + fm*16
    const char* bp = (const char*)pb + (size_t)wv * KT * 8192 + fg * 2048 + fm * 16;

    // A fragment read offset (LDS, f16).
    const int ardoff = fg * A_PITCH + fm * 16;

    floatx4 acc[4][8];
#pragma unroll
    for (int i = 0; i < 4; ++i)
#pragma unroll
        for (int j = 0; j < 8; ++j) acc[i][j] = (floatx4)0.0f;

    // ---- prologue: stage A tile kt=0 into buffer 0 -------------------------
    {
        f32x4 f = *agp;
        union { _Float16 hh[4]; uint2 u; } pk;
        pk.hh[0] = (_Float16)f.x; pk.hh[1] = (_Float16)f.y;
        pk.hh[2] = (_Float16)f.z; pk.hh[3] = (_Float16)f.w;
        *(uint2*)(sA0 + awoff) = pk.u;
    }

    for (int kt = 0; kt < KT; ++kt) {
        const int cur = kt & 1;
        __syncthreads();   // A writes(kt) visible; all reads of other buf done
        const char* ab = cur ? sA1 : sA0;
        const char* bk = bp + (size_t)kt * 8192;

        // A frags from LDS (f16, conflict-light padded layout)
        half8 af[4];
#pragma unroll
        for (int i = 0; i < 4; ++i) af[i] = *(const half8*)(ab + ardoff + i * 256);

        // B frags straight from global -> VGPRs (8 coalesced dwordx4)
        half8 bf[8];
#pragma unroll
        for (int j = 0; j < 8; ++j) bf[j] = *(const half8*)(bk + j * 256);

        // A prefetch for kt+1 (load consumed by cvt before next barrier)
        if (kt + 1 < KT) {
            f32x4 f = agp[(kt + 1) * 8];
            union { _Float16 hh[4]; uint2 u; } pk;
            pk.hh[0] = (_Float16)f.x; pk.hh[1] = (_Float16)f.y;
            pk.hh[2] = (_Float16)f.z; pk.hh[3] = (_Float16)f.w;
            *(uint2*)((cur ? sA0 : sA1) + awoff) = pk.u;
        }

#pragma unroll
        for (int j = 0; j < 8; ++j)
#pragma unroll
            for (int i = 0; i < 4; ++i)
                acc[i][j] = __builtin_amdgcn_mfma_f32_16x16x32_f16(af[i], bf[j], acc[i][j], 0, 0, 0);
    }

    // ---- epilogue: tanh(acc + hproj)*v, reduce over all 1024 cols ----------
    // C layout: col = fm, row(frag) = fg*4 + r.
    float sums[4][4];
#pragma unroll
    for (int i = 0; i < 4; ++i)
#pragma unroll
        for (int r = 0; r < 4; ++r) sums[i][r] = 0.0f;

#pragma unroll
    for (int j = 0; j < 8; ++j) {
        int h = wv * 128 + j * 16 + fm;
        float vv = v[h];
#pragma unroll
        for (int i = 0; i < 4; ++i) {
#pragma unroll
            for (int r = 0; r < 4; ++r) {
                int row = i * 16 + fg * 4 + r;     // 0..63 within slab
                int b = row & 31;                  // r0 % 32 == 0
                float x = acc[i][j][r] + hp[b * HID + h];
                float e2 = __expf(2.0f * x);
                float th = 1.0f - 2.0f / (e2 + 1.0f);
                sums[i][r] += th * vv;
            }
        }
    }
#pragma unroll
    for (int i = 0; i < 4; ++i)
#pragma unroll
        for (int r = 0; r < 4; ++r) {
            float s = sums[i][r];
            s += __shfl_xor(s, 1);
            s += __shfl_xor(s, 2);
            s += __shfl_xor(s, 4);
            s += __shfl_xor(s, 8);
            sums[i][r] = s;
        }
    __syncthreads();                    // done with frag LDS; reuse as reduction
    float* red = (float*)smem;
    if (fm == 0) {
#pragma unroll
        for (int i = 0; i < 4; ++i)
#pragma unroll
            for (int r = 0; r < 4; ++r)
                red[wv * 64 + i * 16 + fg * 4 + r] = sums[i][r];
    }
    __syncthreads();
    if (tid < 64) {
        float tot = 0.0f;
#pragma unroll
        for (int w = 0; w < 8; ++w) tot += red[w * 64 + tid];
        score[r0 + tid] = tot;          // row m = s*32 + b
    }
}

// ---------------------------------------------------------------------------
// Softmax over s per batch b.
// ---------------------------------------------------------------------------
__global__ __launch_bounds__(256) void softmax_kernel(const float* __restrict__ score,
                                                      float* __restrict__ out) {
    int b = blockIdx.x;
    int tid = threadIdx.x;
    __shared__ float redm[4];
    __shared__ float reds[4];
    float vals[8];
    float mx = -1e30f;
#pragma unroll
    for (int k = 0; k < 8; ++k) {
        int s = k * 256 + tid;
        float a = score[(size_t)s * 32 + b];
        vals[k] = a;
        mx = fmaxf(mx, a);
    }
    for (int d = 1; d < 64; d <<= 1) mx = fmaxf(mx, __shfl_xor(mx, d));
    int wv = tid >> 6;
    if ((tid & 63) == 0) redm[wv] = mx;
    __syncthreads();
    mx = fmaxf(fmaxf(redm[0], redm[1]), fmaxf(redm[2], redm[3]));
    float sum = 0.0f;
#pragma unroll
    for (int k = 0; k < 8; ++k) {
        vals[k] = __expf(vals[k] - mx);
        sum += vals[k];
    }
    for (int d = 1; d < 64; d <<= 1) sum += __shfl_xor(sum, d);
    if ((tid & 63) == 0) reds[wv] = sum;
    __syncthreads();
    sum = reds[0] + reds[1] + reds[2] + reds[3];
    float inv = 1.0f / sum;
#pragma unroll
    for (int k = 0; k < 8; ++k) out[b * SEQ + k * 256 + tid] = vals[k] * inv;
}

// ---------------------------------------------------------------------------
extern "C" void kernel_launch(void* const* d_in, const int* in_sizes, int n_in,
                              void* d_out, int out_size, void* d_ws, size_t ws_size,
                              hipStream_t stream) {
    const float* hidden = (const float*)d_in[0];
    const float* enc    = (const float*)d_in[1];
    const float* W      = (const float*)d_in[2];
    const float* bias   = (const float*)d_in[3];
    const float* v      = (const float*)d_in[4];
    float* out = (float*)d_out;

    char* ws = (char*)d_ws;
    _Float16* packB = (_Float16*)ws;                              // 4 MiB
    float* hp       = (float*)(ws + (4u << 20));                  // 128 KiB
    float* score    = (float*)(ws + (4u << 20) + (128u << 10));   // 256 KiB

    pack_b_kernel<<<1024, 256, 0, stream>>>(W, packB);
    hproj_kernel<<<dim3(32, 16), 256, 0, stream>>>(hidden, W, bias, hp);
    attn_gemm_kernel<<<MTOT / 64, 512, 0, stream>>>(enc, packB, hp, v, score);
    softmax_kernel<<<BAT, 256, 0, stream>>>(score, out);
}